// Round 1
// baseline (101.319 us; speedup 1.0000x reference)
//
#include <hip/hip_runtime.h>
#include <math.h>

#define CC 144
#define WW 77
#define KW 10
#define FC 64
#define CONV_OUT 68                 // WW-KW+1
#define H2 128
#define CONCAT (CC*FC + CONV_OUT)   // 9284
#define BLOCK 384

__global__ __launch_bounds__(BLOCK, 1) void fused_mlp_kernel(
    const float* __restrict__ x,      // [CC,WW]
    const float* __restrict__ fc_w,   // [CC,FC,WW]
    const float* __restrict__ fc_b,   // [CC,FC]
    const float* __restrict__ conv_w, // [CC,KW]
    const float* __restrict__ conv_b, // [1]
    const float* __restrict__ w2,     // [H2, CONCAT]
    const float* __restrict__ b2,     // [H2]
    const float* __restrict__ w3,     // [H2]
    const float* __restrict__ b3,     // [1]
    float* __restrict__ out,          // [1]
    float* __restrict__ h_accum,      // ws: [H2], pre-zeroed
    unsigned int* __restrict__ counter) // ws: [1], pre-zeroed
{
    __shared__ float xs[WW];          // one x row (fc blocks)
    __shared__ float vals[CONV_OUT];  // fc outputs (64) or conv outputs (68)
    __shared__ float xfull[CC*WW];    // full x (conv block only)
    __shared__ float cw[CC*KW];       // conv weights (conv block only)
    __shared__ float red[BLOCK/64];
    __shared__ unsigned int is_last;

    const int t = threadIdx.x;
    const int blk = blockIdx.x;

    float hpart = 0.0f;               // t<H2: partial contribution to h[t]

    if (blk < CC) {
        const int c = blk;
        if (t < WW) xs[t] = x[c*WW + t];
        __syncthreads();
        // fc_out[c,d] = dot(fc_w[c,d,:], x[c,:]) + fc_b[c,d]; 4 lanes per d
        if (t < FC*4) {
            const int d = t >> 2, p = t & 3;
            const float* wrow = fc_w + (size_t)(c*FC + d)*WW;
            float s = 0.f;
            for (int w = p; w < WW; w += 4) s += wrow[w] * xs[w];
            s += __shfl_down(s, 2, 4);
            s += __shfl_down(s, 1, 4);
            if (p == 0) vals[d] = s + fc_b[c*FC + d];
        }
        __syncthreads();
        // h[j] += dot(w2[j, c*64 : c*64+64], fc_out[c,:])
        if (t < H2) {
            const float* wrow = w2 + (size_t)t*CONCAT + c*FC;
            float s = 0.f;
            #pragma unroll
            for (int d = 0; d < FC; ++d) s += wrow[d] * vals[d];
            hpart = s;
        }
    } else {
        // conv block: conv[j] = sum_{c,k} x[c, j+k] * conv_w[c,k] + conv_b
        for (int i = t; i < CC*WW; i += BLOCK) xfull[i] = x[i];
        for (int i = t; i < CC*KW; i += BLOCK) cw[i] = conv_w[i];
        __syncthreads();
        if (t < CONV_OUT*4) {
            const int j = t >> 2, p = t & 3;
            float s = 0.f;
            for (int c = p; c < CC; c += 4) {
                const float* xr = xfull + c*WW + j;
                const float* wr = cw + c*KW;
                #pragma unroll
                for (int k = 0; k < KW; ++k) s += xr[k] * wr[k];
            }
            s += __shfl_down(s, 2, 4);
            s += __shfl_down(s, 1, 4);
            if (p == 0) vals[j] = s + conv_b[0];
        }
        __syncthreads();
        // h[j] += dot(w2[j, CC*FC : CC*FC+68], conv[:])
        if (t < H2) {
            const float* wrow = w2 + (size_t)t*CONCAT + CC*FC;
            float s = 0.f;
            #pragma unroll
            for (int j = 0; j < CONV_OUT; ++j) s += wrow[j] * vals[j];
            hpart = s;
        }
    }

    if (t < H2) atomicAdd(&h_accum[t], hpart);
    __threadfence();   // publish this thread's atomic adds before counter bump
    __syncthreads();
    if (t == 0) {
        unsigned int done = atomicAdd(counter, 1u);
        is_last = (done == gridDim.x - 1) ? 1u : 0u;
    }
    __syncthreads();

    if (is_last) {
        // finale: h = relu(h_accum + b2); out = sigmoid(relu(w3 . h + b3))
        float v = 0.f;
        if (t < H2) {
            float hv = atomicAdd(&h_accum[t], 0.0f) + b2[t];  // coherent read
            hv = fmaxf(hv, 0.f);
            v = hv * w3[t];
        }
        // block reduce (BLOCK=384 -> 6 waves; waves 2..5 contribute 0)
        #pragma unroll
        for (int off = 32; off > 0; off >>= 1) v += __shfl_down(v, off, 64);
        if ((t & 63) == 0) red[t >> 6] = v;
        __syncthreads();
        if (t == 0) {
            float s = 0.f;
            #pragma unroll
            for (int i = 0; i < BLOCK/64; ++i) s += red[i];
            s = fmaxf(s + b3[0], 0.f);
            out[0] = 1.0f / (1.0f + expf(-s));
        }
    }
}

extern "C" void kernel_launch(void* const* d_in, const int* in_sizes, int n_in,
                              void* d_out, int out_size, void* d_ws, size_t ws_size,
                              hipStream_t stream) {
    const float* x      = (const float*)d_in[0];
    const float* fc_w   = (const float*)d_in[1];
    const float* fc_b   = (const float*)d_in[2];
    const float* conv_w = (const float*)d_in[3];
    const float* conv_b = (const float*)d_in[4];
    const float* w2     = (const float*)d_in[5];
    const float* b2     = (const float*)d_in[6];
    const float* w3     = (const float*)d_in[7];
    const float* b3     = (const float*)d_in[8];
    float* out = (float*)d_out;

    float* h_accum = (float*)d_ws;
    unsigned int* counter = (unsigned int*)((char*)d_ws + H2*sizeof(float));

    // ws is re-poisoned to 0xAA before every launch: zero the accumulator+counter
    hipMemsetAsync(d_ws, 0, (H2 + 1) * sizeof(float), stream);

    fused_mlp_kernel<<<CC + 1, BLOCK, 0, stream>>>(
        x, fc_w, fc_b, conv_w, conv_b, w2, b2, w3, b3,
        out, h_accum, counter);
}

// Round 2
// 93.817 us; speedup vs baseline: 1.0800x; 1.0800x over previous
//
#include <hip/hip_runtime.h>
#include <math.h>

#define CC 144
#define WW 77
#define KW 10
#define FC 64
#define CONV_OUT 68                 // WW-KW+1
#define H2 128
#define CONCAT (CC*FC + CONV_OUT)   // 9284
#define NBLK (CC + 1)               // 145

// Kernel 1: block c (<144) computes fc_out[c,:] then its 64-wide slice of the
// W2 GEMV; block 144 does the conv row + its 68-wide W2 slice. Each block
// writes a disjoint 128-float partial -> no atomics, no cross-XCD contention.
__global__ __launch_bounds__(256, 1) void partials_kernel(
    const float* __restrict__ x,      // [CC,WW]
    const float* __restrict__ fc_w,   // [CC,FC,WW]
    const float* __restrict__ fc_b,   // [CC,FC]
    const float* __restrict__ conv_w, // [CC,KW]
    const float* __restrict__ conv_b, // [1]
    const float* __restrict__ w2,     // [H2, CONCAT]
    float* __restrict__ partial)      // ws: [NBLK, H2]
{
    __shared__ float xs[WW];
    __shared__ float vals[CONV_OUT];  // fc outputs (64) or conv outputs (68)
    __shared__ float xfull[CC*WW];    // conv block only (44 KB)
    __shared__ float cw[CC*KW];       // conv block only

    const int t = threadIdx.x;
    const int blk = blockIdx.x;

    if (blk < CC) {
        const int c = blk;
        if (t < WW) xs[t] = x[c*WW + t];
        __syncthreads();
        // fc_out[c,d] = dot(fc_w[c,d,:], x[c,:]) + fc_b[c,d]; 4 lanes per d
        {
            const int d = t >> 2, p = t & 3;          // 256 threads = 64 x 4
            const float* wrow = fc_w + (size_t)(c*FC + d)*WW;
            float s = 0.f;
            for (int w = p; w < WW; w += 4) s += wrow[w] * xs[w];
            s += __shfl_down(s, 2, 4);
            s += __shfl_down(s, 1, 4);
            if (p == 0) vals[d] = s + fc_b[c*FC + d];
        }
        __syncthreads();
        // partial[c][j] = dot(w2[j, c*64 : c*64+64], fc_out[c,:])
        if (t < H2) {
            const float* wrow = w2 + (size_t)t*CONCAT + c*FC;
            float s = 0.f;
            #pragma unroll
            for (int d = 0; d < FC; ++d) s += wrow[d] * vals[d];
            partial[(size_t)blk*H2 + t] = s;
        }
    } else {
        // conv[j] = sum_{c,k} x[c, j+k] * conv_w[c,k] + conv_b
        for (int i = t; i < CC*WW; i += 256) xfull[i] = x[i];
        for (int i = t; i < CC*KW; i += 256) cw[i] = conv_w[i];
        __syncthreads();
        if (t < CONV_OUT*2) {
            const int j = t >> 1, p = t & 1;          // 2 lanes per output
            float s = 0.f;
            for (int c = p; c < CC; c += 2) {
                const float* xr = xfull + c*WW + j;
                const float* wr = cw + c*KW;
                #pragma unroll
                for (int k = 0; k < KW; ++k) s += xr[k] * wr[k];
            }
            s += __shfl_down(s, 1, 2);
            if (p == 0) vals[j] = s + conv_b[0];
        }
        __syncthreads();
        // partial[144][j] = dot(w2[j, CC*FC : CC*FC+68], conv[:])
        if (t < H2) {
            const float* wrow = w2 + (size_t)t*CONCAT + CC*FC;
            float s = 0.f;
            #pragma unroll
            for (int j = 0; j < CONV_OUT; ++j) s += wrow[j] * vals[j];
            partial[(size_t)blk*H2 + t] = s;
        }
    }
}

// Kernel 2: reduce 145 partials, bias+relu, dot with w3, relu+sigmoid.
__global__ __launch_bounds__(128, 1) void finale_kernel(
    const float* __restrict__ partial, // [NBLK, H2]
    const float* __restrict__ b2,      // [H2]
    const float* __restrict__ w3,      // [H2]
    const float* __restrict__ b3,      // [1]
    float* __restrict__ out)           // [1]
{
    __shared__ float red[2];
    const int t = threadIdx.x;

    float s = b2[t];
    for (int b = 0; b < NBLK; ++b)      // coalesced: lane t reads partial[b][t]
        s += partial[(size_t)b*H2 + t];
    s = fmaxf(s, 0.f);
    float v = s * w3[t];

    #pragma unroll
    for (int off = 32; off > 0; off >>= 1) v += __shfl_down(v, off, 64);
    if ((t & 63) == 0) red[t >> 6] = v;
    __syncthreads();
    if (t == 0) {
        float r = fmaxf(red[0] + red[1] + b3[0], 0.f);
        out[0] = 1.0f / (1.0f + expf(-r));
    }
}

extern "C" void kernel_launch(void* const* d_in, const int* in_sizes, int n_in,
                              void* d_out, int out_size, void* d_ws, size_t ws_size,
                              hipStream_t stream) {
    const float* x      = (const float*)d_in[0];
    const float* fc_w   = (const float*)d_in[1];
    const float* fc_b   = (const float*)d_in[2];
    const float* conv_w = (const float*)d_in[3];
    const float* conv_b = (const float*)d_in[4];
    const float* w2     = (const float*)d_in[5];
    const float* b2     = (const float*)d_in[6];
    const float* w3     = (const float*)d_in[7];
    const float* b3     = (const float*)d_in[8];
    float* out = (float*)d_out;

    float* partial = (float*)d_ws;   // [NBLK * H2] floats, fully overwritten

    partials_kernel<<<NBLK, 256, 0, stream>>>(
        x, fc_w, fc_b, conv_w, conv_b, w2, partial);
    finale_kernel<<<1, 128, 0, stream>>>(partial, b2, w3, b3, out);
}